// Round 1
// baseline (674.128 us; speedup 1.0000x reference)
//
#include <hip/hip_runtime.h>

// ---- problem constants ----
#define ATTN_S  2048
#define ATTN_D  64
#define ATTN_BH 32           // B*H = 2*16
#define QT      128          // q rows per block
#define KT      64           // k cols per tile iteration
#define NWAVE   8            // 512 threads
#define LOG2E   1.4426950408889634f

typedef _Float16 half8 __attribute__((ext_vector_type(8)));
typedef _Float16 half4v __attribute__((ext_vector_type(4)));
typedef _Float16 half2v __attribute__((ext_vector_type(2)));
typedef float    floatx4 __attribute__((ext_vector_type(4)));

static __device__ __forceinline__ float fast_exp2(float x) {
#if __has_builtin(__builtin_amdgcn_exp2f)
  return __builtin_amdgcn_exp2f(x);
#else
  return exp2f(x);
#endif
}

// One block: (bh, q-tile of 128 rows). 8 waves, wave w owns 16 q rows.
// Pass A: m = max(s), L = sum exp(s) over full row (s already scaled by 1/8 via
//         exact prescale of Q). Pass B: recompute s, p = exp(s)/(e^m + L),
//         write p, accumulate out += p*V via MFMA (p round-trips LDS for the
//         C-layout -> A-layout transform).
__global__ __launch_bounds__(512)
void attn_softmax1_kernel(const float* __restrict__ Q,
                          const float* __restrict__ K,
                          const float* __restrict__ V,
                          float* __restrict__ Out,
                          float* __restrict__ P)
{
  __shared__ _Float16 sK[KT][72];        // K tile, fp16, row-major [kj][d], pad->144B pitch
  __shared__ _Float16 sV[ATTN_D][72];    // V tile TRANSPOSED: sV[d][kj]
  __shared__ float    sP[NWAVE][16][68]; // per-wave p tile [qrow][kcol], pad->272B pitch

  const int tid  = threadIdx.x;
  const int w    = tid >> 6;
  const int lane = tid & 63;
  const int quad = lane >> 4;
  const int l15  = lane & 15;

  const int bh = blockIdx.x >> 4;            // 32 (b,h) pairs
  const int q0 = (blockIdx.x & 15) * QT;     // 16 q-tiles

  const float* Qb = Q + (size_t)bh * ATTN_S * ATTN_D;
  const float* Kb = K + (size_t)bh * ATTN_S * ATTN_D;
  const float* Vb = V + (size_t)bh * ATTN_S * ATTN_D;
  float*       Ob = Out + (size_t)bh * ATTN_S * ATTN_D;
  float*       Pb = P + (size_t)bh * (size_t)ATTN_S * ATTN_S;

  // ---- Q fragments (A-operand layout: A[m=lane&15][k=quad*8+j]), exact 1/8 prescale ----
  const int qrow = q0 + w * 16 + l15;
  half8 aq[2];
  {
    const float* qr = Qb + (size_t)qrow * ATTN_D;
#pragma unroll
    for (int ch = 0; ch < 2; ++ch) {
      const floatx4* qv = (const floatx4*)(qr + ch * 32 + quad * 8);
      floatx4 f0 = qv[0], f1 = qv[1];
#pragma unroll
      for (int j = 0; j < 4; ++j) {
        aq[ch][j]     = (_Float16)(f0[j] * 0.125f);
        aq[ch][4 + j] = (_Float16)(f1[j] * 0.125f);
      }
    }
  }

  // ================= Pass A: row max + sum of exp =================
  float mrow[4], lrow[4];
#pragma unroll
  for (int r = 0; r < 4; ++r) { mrow[r] = -3.0e38f; lrow[r] = 0.0f; }

#pragma unroll 1
  for (int kt = 0; kt < ATTN_S; kt += KT) {
    __syncthreads();
    // stage K tile -> fp16 LDS (coalesced float4 reads)
#pragma unroll
    for (int i = 0; i < 2; ++i) {
      int idx = tid + 512 * i;                 // 0..1023
      int r = idx >> 4, c4 = idx & 15;
      floatx4 f = *(const floatx4*)(Kb + (size_t)(kt + r) * ATTN_D + c4 * 4);
      half4v h = { (_Float16)f[0], (_Float16)f[1], (_Float16)f[2], (_Float16)f[3] };
      *(half4v*)&sK[r][c4 * 4] = h;
    }
    __syncthreads();

#pragma unroll
    for (int n = 0; n < 4; ++n) {
      half8 bk0 = *(const half8*)&sK[n * 16 + l15][quad * 8];
      half8 bk1 = *(const half8*)&sK[n * 16 + l15][32 + quad * 8];
      floatx4 acc = {0.f, 0.f, 0.f, 0.f};
      acc = __builtin_amdgcn_mfma_f32_16x16x32_f16(aq[0], bk0, acc, 0, 0, 0);
      acc = __builtin_amdgcn_mfma_f32_16x16x32_f16(aq[1], bk1, acc, 0, 0, 0);
#pragma unroll
      for (int r = 0; r < 4; ++r) {
        float s = acc[r];
        mrow[r] = fmaxf(mrow[r], s);
        lrow[r] += fast_exp2(s * LOG2E);
      }
    }
  }

  // reduce across the 16 lanes sharing each row (xor butterfly stays in-group)
  float rrow[4];
#pragma unroll
  for (int r = 0; r < 4; ++r) {
    float m = mrow[r], l = lrow[r];
#pragma unroll
    for (int off = 1; off < 16; off <<= 1) {
      m = fmaxf(m, __shfl_xor(m, off, 64));
      l += __shfl_xor(l, off, 64);
    }
    // denom = e^m + sum exp(s)  ==  e^m * (1 + sum exp(s-m))  (reference semantics)
    rrow[r] = 1.0f / (fast_exp2(m * LOG2E) + l);
  }

  // ================= Pass B: recompute s, write p, out += p*V =================
  floatx4 oacc[4];
#pragma unroll
  for (int d = 0; d < 4; ++d) oacc[d] = (floatx4){0.f, 0.f, 0.f, 0.f};

#pragma unroll 1
  for (int kt = 0; kt < ATTN_S; kt += KT) {
    __syncthreads();
    // stage K tile
#pragma unroll
    for (int i = 0; i < 2; ++i) {
      int idx = tid + 512 * i;
      int r = idx >> 4, c4 = idx & 15;
      floatx4 f = *(const floatx4*)(Kb + (size_t)(kt + r) * ATTN_D + c4 * 4);
      half4v h = { (_Float16)f[0], (_Float16)f[1], (_Float16)f[2], (_Float16)f[3] };
      *(half4v*)&sK[r][c4 * 4] = h;
    }
    // stage V tile transposed: sV[d][kj] = V[kt+kj][d]; paired rows -> dword writes
    {
      int rp = tid >> 4, c4 = tid & 15;        // rp: 0..31 row-pairs
      floatx4 f0 = *(const floatx4*)(Vb + (size_t)(kt + 2 * rp) * ATTN_D + c4 * 4);
      floatx4 f1 = *(const floatx4*)(Vb + (size_t)(kt + 2 * rp + 1) * ATTN_D + c4 * 4);
#pragma unroll
      for (int c = 0; c < 4; ++c) {
        half2v h = { (_Float16)f0[c], (_Float16)f1[c] };
        *(half2v*)&sV[c4 * 4 + c][2 * rp] = h;
      }
    }
    __syncthreads();

    // recompute scores, p = exp(s) * rrow -> sP (C-layout write)
#pragma unroll
    for (int n = 0; n < 4; ++n) {
      half8 bk0 = *(const half8*)&sK[n * 16 + l15][quad * 8];
      half8 bk1 = *(const half8*)&sK[n * 16 + l15][32 + quad * 8];
      floatx4 acc = {0.f, 0.f, 0.f, 0.f};
      acc = __builtin_amdgcn_mfma_f32_16x16x32_f16(aq[0], bk0, acc, 0, 0, 0);
      acc = __builtin_amdgcn_mfma_f32_16x16x32_f16(aq[1], bk1, acc, 0, 0, 0);
#pragma unroll
      for (int r = 0; r < 4; ++r) {
        float p = fast_exp2(acc[r] * LOG2E) * rrow[r];
        sP[w][quad * 4 + r][n * 16 + l15] = p;
      }
    }
    // intra-wave LDS is in-order: A-layout read-back needs no barrier (per-wave buffer)
#pragma unroll
    for (int ch = 0; ch < 2; ++ch) {
      const float* prow = &sP[w][l15][ch * 32 + quad * 8];
      half8 ap;
#pragma unroll
      for (int j = 0; j < 8; ++j) ap[j] = (_Float16)prow[j];
#pragma unroll
      for (int ds = 0; ds < 4; ++ds) {
        half8 bv = *(const half8*)&sV[ds * 16 + l15][ch * 32 + quad * 8];
        oacc[ds] = __builtin_amdgcn_mfma_f32_16x16x32_f16(ap, bv, oacc[ds], 0, 0, 0);
      }
    }
    // store p tile: row-major, 16 lanes x float4 = 256B per row
    {
      const int growbase = q0 + w * 16;
#pragma unroll
      for (int i = 0; i < 4; ++i) {
        int r = i * 4 + quad;
        floatx4 val = *(const floatx4*)&sP[w][r][l15 * 4];
        *(floatx4*)(Pb + (size_t)(growbase + r) * ATTN_S + kt + l15 * 4) = val;
      }
    }
  }

  // ---- epilogue: write out (C-layout: row=quad*4+r, col=ds*16+l15) ----
  {
    const int grow = q0 + w * 16 + quad * 4;
#pragma unroll
    for (int ds = 0; ds < 4; ++ds)
#pragma unroll
      for (int r = 0; r < 4; ++r)
        Ob[(size_t)(grow + r) * ATTN_D + ds * 16 + l15] = oacc[ds][r];
  }
}

extern "C" void kernel_launch(void* const* d_in, const int* in_sizes, int n_in,
                              void* d_out, int out_size, void* d_ws, size_t ws_size,
                              hipStream_t stream) {
  const float* Q = (const float*)d_in[0];
  const float* K = (const float*)d_in[1];
  const float* V = (const float*)d_in[2];
  float* Out = (float*)d_out;
  float* P   = Out + (size_t)ATTN_BH * ATTN_S * ATTN_D;  // out first, then p_attn

  dim3 grid(ATTN_BH * (ATTN_S / QT));  // 32 * 16 = 512 blocks
  dim3 block(512);
  attn_softmax1_kernel<<<grid, block, 0, stream>>>(Q, K, V, Out, P);
}